// Round 7
// baseline (364.248 us; speedup 1.0000x reference)
//
#include <hip/hip_runtime.h>
#include <stdint.h>

#define TREES 8192
#define HID   256
#define CH    16
#define KL    4
#define G     8            // trees per group
#define NG    2            // groups per block -> 16 trees/block
#define GB    (G * NG)
#define LDSS  264          // padded stride for hs / fallback A

typedef short bf16x8 __attribute__((ext_vector_type(8)));
typedef float f32x4  __attribute__((ext_vector_type(4)));

__device__ __forceinline__ unsigned short f2bf(float f) {
    unsigned u = __builtin_bit_cast(unsigned, f);
    u += 0x7FFFu + ((u >> 16) & 1u);
    return (unsigned short)(u >> 16);
}
__device__ __forceinline__ float elu1(float x) {
    return x > 0.f ? x : (__expf(x) - 1.f);
}
__device__ __forceinline__ uint4 pack8(float4 a, float4 b) {
    union { uint4 u4; unsigned short s[8]; } U;
    U.s[0] = f2bf(a.x); U.s[1] = f2bf(a.y); U.s[2] = f2bf(a.z); U.s[3] = f2bf(a.w);
    U.s[4] = f2bf(b.x); U.s[5] = f2bf(b.y); U.s[6] = f2bf(b.z); U.s[7] = f2bf(b.w);
    return U.u4;
}
__device__ __forceinline__ void gload_lds16(const void* g, void* l) {
    __builtin_amdgcn_global_load_lds(
        (const __attribute__((address_space(1))) void*)g,
        (__attribute__((address_space(3))) void*)l, 16, 0, 0);
}

// ---- Prep: tiled transpose fp32 [h][d] -> bf16 [d][h], coalesced both sides.
__global__ void prep_transpose(const float* __restrict__ Wz,
                               const float* __restrict__ Wzf,
                               const float* __restrict__ bz,
                               unsigned short* __restrict__ WzT,
                               unsigned short* __restrict__ WzfT,
                               float* __restrict__ bzsum) {
    __shared__ unsigned short ts[64][65];
    const int k  = blockIdx.z;
    const int h0 = blockIdx.x * 64;
    const int d0 = blockIdx.y * 64;
    const float* src = (k < KL) ? (Wz + (k << 16)) : Wzf;
    unsigned short* dst = (k < KL) ? (WzT + (k << 16)) : WzfT;
    const int tid = threadIdx.x;
    const int jc  = tid & 63;
    #pragma unroll
    for (int r = 0; r < 16; ++r) {
        int i = r * 4 + (tid >> 6);
        ts[jc][i] = f2bf(src[(h0 + i) * HID + d0 + jc]);
    }
    __syncthreads();
    #pragma unroll
    for (int r = 0; r < 16; ++r) {
        int jl = r * 4 + (tid >> 6);
        dst[(d0 + jl) * HID + h0 + jc] = ts[jl][jc];
    }
    if (k == KL && blockIdx.x == 0 && blockIdx.y == 0) {
        float s = 0.f;
        #pragma unroll
        for (int kk = 0; kk < KL; ++kk) s += bz[kk * HID + tid];
        bzsum[tid] = s;
    }
}

// ---- G: materialize gathered leaf rows as bf16 in the MFMA-ready layout.
// dataB cell index = halfidx*2048 + gg*256 + ch2*16 + row  (16B cells), where
// halfidx = (t>>3)*2 + hh, t = tree, hh = h-half, gg = t&7, ch2 = 16B chunk
// within half, row = child. Writes are wave-linear (coalesced 1KB); reads are
// scattered 32B absorbed by L2/L3. Pure streaming kernel: measures the true
// cost of the random gather, isolated from compute.
__global__ __launch_bounds__(256) void gather_kernel(
    const float* __restrict__ x, const int* __restrict__ leaf,
    unsigned short* __restrict__ dataB, int nrows)
{
    const int cid = blockIdx.x * 256 + threadIdx.x;   // 0 .. 4,194,303
    const int halfidx = cid >> 11;                    // 0..2047
    const int w    = cid & 2047;
    const int gg   = w >> 8;                          // 0..7
    const int ch2  = (w >> 4) & 15;
    const int row  = w & 15;
    const int t    = (halfidx >> 1) * 8 + gg;
    const int ch   = (halfidx & 1) * 16 + ch2;
    int idx = leaf[t * CH + row];
    idx = ((unsigned)idx < (unsigned)nrows) ? idx : 0;
    const float* src = x + (size_t)idx * HID + ch * 8;
    float4 v0 = *(const float4*)src;
    float4 v1 = *(const float4*)(src + 4);
    *(uint4*)&dataB[(size_t)cid * 8] = pack8(v0, v1);
}

// ---- M: compute kernel fed by linear DMA. 16 trees/block = 2 groups of 8;
// pipelined at h-half granularity: stage half i+1 (32KB, 8 global_load_lds
// per thread, issue-and-forget) while running half i's 16 MFMA steps.
// Groups of 8 keep per-block WzT streaming at 1MB (L2-BW constraint).
__global__ __launch_bounds__(256, 2) void ptree_pipe(
    const unsigned short* __restrict__ dataB,
    const float* __restrict__ bzf,
    const unsigned short* __restrict__ WzT,
    const unsigned short* __restrict__ WzfT,
    const float* __restrict__ bzsum,
    float* __restrict__ out)
{
    __shared__ __align__(16) unsigned short shH[2][16384];  // 2 x 32 KB
    __shared__ __align__(16) unsigned short hs[GB][LDSS];   // 8.4 KB
    const int tid  = threadIdx.x;
    const int lane = tid & 63;
    const int wave = tid >> 6;
    const int ncol = lane & 15;
    const int quad = lane >> 4;
    const int t0   = blockIdx.x * GB;

    const size_t hbase = (size_t)blockIdx.x * 4 * 16384;  // 4 halves, 16384 shorts each

    // stage half 0
    #pragma unroll
    for (int i = 0; i < 8; ++i) {
        const int c2 = i * 256 + tid;
        gload_lds16(dataB + hbase + c2 * 8, &shH[0][c2 * 8]);
    }

    float bzs[4], bzfv[4];
    #pragma unroll
    for (int nt = 0; nt < 4; ++nt) {
        bzs[nt]  = bzsum[wave * 64 + nt * 16 + ncol];
        bzfv[nt] = bzf[wave * 64 + nt * 16 + ncol];
    }

    const unsigned short* wz_base = WzT + (wave * 64 + ncol) * HID + quad * 8;
    // global step S = half*16 + st: k=(S>>2)&3, kt_g=((S>>4)&1)*4 + (S&3)
    bf16x8 bc[4], bn[4];
    #pragma unroll
    for (int nt = 0; nt < 4; ++nt)
        bc[nt] = *(const bf16x8*)(wz_base + nt * 16 * HID);   // S=0

    __syncthreads();   // half 0 + B prologue ready

    f32x4 acc[G][4];
    for (int half = 0; half < 4; ++half) {
        const int hb = half & 1;
        if (!(half & 1)) {
            #pragma unroll
            for (int g = 0; g < G; ++g)
                #pragma unroll
                for (int nt = 0; nt < 4; ++nt) acc[g][nt] = f32x4{0.f, 0.f, 0.f, 0.f};
        }
        if (half < 3) {   // stage next half into the other buffer
            const size_t nb = hbase + (size_t)(half + 1) * 16384;
            #pragma unroll
            for (int i = 0; i < 8; ++i) {
                const int c2 = i * 256 + tid;
                gload_lds16(dataB + nb + c2 * 8, &shH[hb ^ 1][c2 * 8]);
            }
        }
        #pragma unroll 2
        for (int st = 0; st < 16; ++st) {
            const int S  = half * 16 + st;
            const int Sn = (S < 63) ? S + 1 : S;
            const unsigned short* pn =
                wz_base + ((Sn >> 2) & 3) * 65536 + (((Sn >> 4) & 1) * 4 + (Sn & 3)) * 32;
            #pragma unroll
            for (int nt = 0; nt < 4; ++nt)
                bn[nt] = *(const bf16x8*)(pn + nt * 16 * HID);
            const int k    = (S >> 2) & 3;
            const int ktl  = S & 3;
            const int arow = (ncol - k) & 15;
            const int abase = (ktl * 4 + quad) * 128 + arow * 8;   // [ch2][row][8]
            #pragma unroll
            for (int g = 0; g < G; ++g) {
                bf16x8 a = *(const bf16x8*)&shH[hb][g * 2048 + abase];
                #pragma unroll
                for (int nt = 0; nt < 4; ++nt)
                    acc[g][nt] = __builtin_amdgcn_mfma_f32_16x16x32_bf16(
                        a, bc[nt], acc[g][nt], 0, 0, 0);
            }
            #pragma unroll
            for (int nt = 0; nt < 4; ++nt) bc[nt] = bn[nt];
        }
        if (half & 1) {   // group (half>>1) complete: hsum -> hs rows
            const int grp = half >> 1;
            #pragma unroll
            for (int g = 0; g < G; ++g)
                #pragma unroll
                for (int nt = 0; nt < 4; ++nt) {
                    float sv = 0.f;
                    #pragma unroll
                    for (int r = 0; r < 4; ++r) sv += elu1(acc[g][nt][r] + bzs[nt]);
                    sv += __shfl_xor(sv, 16);
                    sv += __shfl_xor(sv, 32);
                    if (quad == 0) hs[grp * G + g][wave * 64 + nt * 16 + ncol] = f2bf(sv);
                }
        }
        __syncthreads();   // DMA(half+1) landed; buffer hb free
    }

    // ---- GEMM2: all 16 hs rows valid -> dense.
    f32x4 acc2[4];
    #pragma unroll
    for (int nt = 0; nt < 4; ++nt) acc2[nt] = f32x4{0.f, 0.f, 0.f, 0.f};
    const unsigned short* wzf_base = WzfT + (wave * 64 + ncol) * HID + quad * 8;
    #pragma unroll 2
    for (int kt = 0; kt < 8; ++kt) {
        bf16x8 a = *(const bf16x8*)&hs[ncol][kt * 32 + quad * 8];
        #pragma unroll
        for (int nt = 0; nt < 4; ++nt) {
            bf16x8 b = *(const bf16x8*)(wzf_base + nt * 16 * HID + kt * 32);
            acc2[nt] = __builtin_amdgcn_mfma_f32_16x16x32_bf16(a, b, acc2[nt], 0, 0, 0);
        }
    }
    #pragma unroll
    for (int nt = 0; nt < 4; ++nt)
        #pragma unroll
        for (int r = 0; r < 4; ++r) {
            const int tree = quad * 4 + r;
            float v = elu1(acc2[nt][r] + 16.f * bzfv[nt]);
            out[(size_t)(t0 + tree) * HID + wave * 64 + nt * 16 + ncol] = v;
        }
}

// ---- Fallback (r5 verbatim): used when workspace can't hold dataB.
__global__ __launch_bounds__(256, 2) void ptree_kernel(
    const float* __restrict__ x, const int* __restrict__ leaf,
    const float* __restrict__ bzf, const unsigned short* __restrict__ WzT,
    const unsigned short* __restrict__ WzfT, const float* __restrict__ bzsum,
    float* __restrict__ out, int nrows)
{
    __shared__ __align__(16) unsigned short sh[G][CH][LDSS];
    __shared__ __align__(16) unsigned short hs[GB][LDSS];
    const int tid  = threadIdx.x;
    const int lane = tid & 63;
    const int wave = tid >> 6;
    const int t0   = blockIdx.x * GB;
    const int ncol = lane & 15;
    const int quad = lane >> 4;

    float bzs[4], bzfv[4];
    #pragma unroll
    for (int nt = 0; nt < 4; ++nt) {
        bzs[nt]  = bzsum[wave * 64 + nt * 16 + ncol];
        bzfv[nt] = bzf[wave * 64 + nt * 16 + ncol];
    }
    const unsigned short* wz_base = WzT + (wave * 64 + ncol) * HID + quad * 8;

    for (int grp = 0; grp < NG; ++grp) {
        const int tg = t0 + grp * G;
        #pragma unroll
        for (int i = 0; i < (G * CH * 32) / 256; ++i) {
            int cid = i * 256 + tid;
            int g   = cid >> 9;
            int row = (cid >> 5) & 15;
            int ch  = cid & 31;
            int idx = leaf[(tg + g) * CH + row];
            idx = ((unsigned)idx < (unsigned)nrows) ? idx : 0;
            const float* src = x + (size_t)idx * HID + ch * 8;
            float4 v0 = *(const float4*)src;
            float4 v1 = *(const float4*)(src + 4);
            *(uint4*)&sh[g][row][ch * 8] = pack8(v0, v1);
        }
        __syncthreads();

        f32x4 acc1[G][4];
        #pragma unroll
        for (int g = 0; g < G; ++g)
            #pragma unroll
            for (int nt = 0; nt < 4; ++nt) acc1[g][nt] = f32x4{0.f, 0.f, 0.f, 0.f};

        bf16x8 bc[4], bn[4];
        #pragma unroll
        for (int nt = 0; nt < 4; ++nt)
            bc[nt] = *(const bf16x8*)(wz_base + nt * 16 * HID);

        #pragma unroll 2
        for (int s = 0; s < KL * 8; ++s) {
            const int sn = (s < KL * 8 - 1) ? s + 1 : s;
            const unsigned short* pn = wz_base + (sn >> 3) * 65536 + (sn & 7) * 32;
            #pragma unroll
            for (int nt = 0; nt < 4; ++nt)
                bn[nt] = *(const bf16x8*)(pn + nt * 16 * HID);
            const int k    = s >> 3;
            const int kt   = s & 7;
            const int arow = (ncol - k) & 15;
            #pragma unroll
            for (int g = 0; g < G; ++g) {
                bf16x8 a = *(const bf16x8*)&sh[g][arow][kt * 32 + quad * 8];
                #pragma unroll
                for (int nt = 0; nt < 4; ++nt)
                    acc1[g][nt] = __builtin_amdgcn_mfma_f32_16x16x32_bf16(
                        a, bc[nt], acc1[g][nt], 0, 0, 0);
            }
            #pragma unroll
            for (int nt = 0; nt < 4; ++nt) bc[nt] = bn[nt];
        }

        #pragma unroll
        for (int g = 0; g < G; ++g)
            #pragma unroll
            for (int nt = 0; nt < 4; ++nt) {
                float sv = 0.f;
                #pragma unroll
                for (int r = 0; r < 4; ++r) sv += elu1(acc1[g][nt][r] + bzs[nt]);
                sv += __shfl_xor(sv, 16);
                sv += __shfl_xor(sv, 32);
                if (quad == 0) hs[grp * G + g][wave * 64 + nt * 16 + ncol] = f2bf(sv);
            }
        __syncthreads();
    }

    f32x4 acc2[4];
    #pragma unroll
    for (int nt = 0; nt < 4; ++nt) acc2[nt] = f32x4{0.f, 0.f, 0.f, 0.f};
    const unsigned short* wzf_base = WzfT + (wave * 64 + ncol) * HID + quad * 8;
    #pragma unroll 2
    for (int kt = 0; kt < 8; ++kt) {
        bf16x8 a = *(const bf16x8*)&hs[ncol][kt * 32 + quad * 8];
        #pragma unroll
        for (int nt = 0; nt < 4; ++nt) {
            bf16x8 b = *(const bf16x8*)(wzf_base + nt * 16 * HID + kt * 32);
            acc2[nt] = __builtin_amdgcn_mfma_f32_16x16x32_bf16(a, b, acc2[nt], 0, 0, 0);
        }
    }
    #pragma unroll
    for (int nt = 0; nt < 4; ++nt)
        #pragma unroll
        for (int r = 0; r < 4; ++r) {
            const int tree = quad * 4 + r;
            float v = elu1(acc2[nt][r] + 16.f * bzfv[nt]);
            out[(size_t)(t0 + tree) * HID + wave * 64 + nt * 16 + ncol] = v;
        }
}

extern "C" void kernel_launch(void* const* d_in, const int* in_sizes, int n_in,
                              void* d_out, int out_size, void* d_ws, size_t ws_size,
                              hipStream_t stream) {
    (void)out_size;
    const void* p_x = nullptr; const void* p_Wz = nullptr; const void* p_bz = nullptr;
    const void* p_Wzf = nullptr; const void* p_bzf = nullptr; const void* p_leaf = nullptr;
    for (int i = 0; i < n_in; ++i) {
        switch (in_sizes[i]) {
            case 200000 * 256:   p_x    = d_in[i]; break;
            case KL * 256 * 256: p_Wz   = d_in[i]; break;
            case KL * 256:       p_bz   = d_in[i]; break;
            case 256 * 256:      p_Wzf  = d_in[i]; break;
            case 256:            p_bzf  = d_in[i]; break;
            case TREES * CH:     p_leaf = d_in[i]; break;
        }
    }
    const float* x    = (const float*)p_x;
    const float* Wz   = (const float*)p_Wz;
    const float* bz   = (const float*)p_bz;
    const float* Wzf  = (const float*)p_Wzf;
    const float* bzf  = (const float*)p_bzf;
    const int*   leaf = (const int*)p_leaf;

    const size_t dataB_shorts = (size_t)TREES * CH * HID;          // 33.55M shorts
    const size_t needA = dataB_shorts * 2 + 524288 + 131072 + 1024; // ~67.8 MB

    dim3 tg(4, 4, KL + 1);
    if (ws_size >= needA) {
        unsigned short* dataB = (unsigned short*)d_ws;
        unsigned short* WzT   = dataB + dataB_shorts;
        unsigned short* WzfT  = WzT + KL * HID * HID;
        float*          bzsum = (float*)(WzfT + HID * HID);
        prep_transpose<<<tg, 256, 0, stream>>>(Wz, Wzf, bz, WzT, WzfT, bzsum);
        gather_kernel<<<(TREES * CH * 32) / 256, 256, 0, stream>>>(x, leaf, dataB, 200000);
        ptree_pipe<<<TREES / GB, 256, 0, stream>>>(dataB, bzf, WzT, WzfT, bzsum,
                                                   (float*)d_out);
    } else {
        unsigned short* WzT   = (unsigned short*)d_ws;
        unsigned short* WzfT  = WzT + KL * HID * HID;
        float*          bzsum = (float*)(WzfT + HID * HID);
        prep_transpose<<<tg, 256, 0, stream>>>(Wz, Wzf, bz, WzT, WzfT, bzsum);
        ptree_kernel<<<TREES / GB, 256, 0, stream>>>(x, leaf, bzf, WzT, WzfT, bzsum,
                                                     (float*)d_out, 200000);
    }
}